// Round 11
// baseline (59.594 us; speedup 1.0000x reference)
//
#include <hip/hip_runtime.h>
#include <hip/hip_bf16.h>
#include <math.h>

#define B_N 16
#define C_IN 64
#define H_N 128
#define W_N 128
#define C_OUT 128

typedef __attribute__((ext_vector_type(8))) short short8v;   // 8 bf16 (4 VGPR)
typedef __attribute__((ext_vector_type(4))) float float4v;

__device__ __forceinline__ unsigned short f2bf(float f) {
  union { float f; unsigned u; } c; c.f = f;
  unsigned u = c.u + 0x7fffu + ((c.u >> 16) & 1u);   // RNE
  return (unsigned short)(u >> 16);
}

// ---------------------------------------------------------------------------
// Prep: pack weights into per-lane B-fragment order (bf16) AND per-block
// partial sums of w^2 (each element read exactly once -> deterministic).
// frag id = (kh*6 + s)*8 + nt ; lane l supplies B[k=s*32+(l>>4)*8+j][n=nt*16+(l&15)]
// ---------------------------------------------------------------------------
__global__ __launch_bounds__(256) void scs_prep_w(
    const float* __restrict__ w, unsigned short* __restrict__ wf,
    float* __restrict__ partial)
{
  __shared__ float red[256];
  const int t    = threadIdx.x;
  const int gid  = blockIdx.x * 256 + t;            // 0..9215
  const int frag = gid >> 6;                        // 0..143
  const int l    = gid & 63;
  const int kh   = frag / 48;
  const int rem  = frag % 48;
  const int s    = rem >> 3;
  const int nt   = rem & 7;
  const int kb   = kh * 192 + s * 32 + (l >> 4) * 8;
  const int n    = nt * 16 + (l & 15);
  short8v pk;
  float ss = 0.f;
#pragma unroll
  for (int j = 0; j < 8; ++j) {
    const float v = w[(size_t)(kb + j) * C_OUT + n];
    ss = fmaf(v, v, ss);
    pk[j] = (short)f2bf(v);
  }
  *reinterpret_cast<short8v*>(wf + (size_t)frag * 512 + l * 8) = pk;
  red[t] = ss;
  __syncthreads();
  for (int off = 128; off > 0; off >>= 1) {
    if (t < off) red[t] += red[t + off];
    __syncthreads();
  }
  if (t == 0) partial[blockIdx.x] = red[0];
}

// ---------------------------------------------------------------------------
// Main v5: block = (b, output rows h0,h0+1). 1024 blocks, 512 threads.
// Schedule: stage 4 rows -> ONE barrier -> MFMA loop (B-frags prefetched at
// top of each K-step; A ds_reads per input row) -> pl phase (direct from
// psacc, no Ss) -> barrier -> epilogue. Scalar prep deferred past MFMA.
// ---------------------------------------------------------------------------
__global__ __launch_bounds__(512, 4) void scs_main(
    const float* __restrict__ x, const unsigned short* __restrict__ wf,
    const float* __restrict__ bias, const float* __restrict__ q,
    const float* __restrict__ p, const float* __restrict__ partial,
    float* __restrict__ out)
{
  __shared__ alignas(16) char xT[4 * 16640];   // 4 rows x 130 slots x 128B (65KB)
  __shared__ float psacc[4][4][128];           // 8KB  [cc][row][w]
  __shared__ float pl[2][128];                 // 1KB   (total 75.8KB -> 2 blk/CU)

  const int t   = threadIdx.x;
  const int l   = t & 63;
  const int wid = t >> 6;
  const int wm  = wid >> 2;        // 0..1  (M half: 64 pixels)
  const int wn  = wid & 3;         // 0..3  (N quarter: 32 couts)
  const int lr  = l & 15;
  const int lg  = l >> 4;
  const int bid = blockIdx.x;
  const int swz = (bid & 7) * 128 + (bid >> 3);   // bijective XCD remap (1024%8==0)
  const int b   = swz >> 6;
  const int h0  = (swz & 63) << 1;

  // zero the w-pad slots (jr=0 and jr=129) of all 4 rows
  if (t < 64) {
    const int k   = t >> 3;                 // 0..7
    const int row = k >> 1;
    const int jr  = (k & 1) ? 129 : 0;
    *reinterpret_cast<float4v*>(xT + row * 16640 + jr * 128 + (t & 7) * 16) =
        float4v{0.f, 0.f, 0.f, 0.f};
  }

  // ---- stage 4 input rows -> bf16 xT (transposed, swizzled); fp32 squares --
  const int wcol  = t & 127;
  const int cbase = t >> 7;                 // 0..3
  float part0 = 0.f, part1 = 0.f, part2 = 0.f, part3 = 0.f;
#pragma unroll
  for (int it = 0; it < 8; ++it) {
    const int  row4  = it >> 1;             // compile-time
    const int  cc    = (it & 1) * 4 + cbase;
    const int  inr   = h0 - 1 + row4;
    const bool valid = (unsigned)inr < 128u;   // block-uniform per iteration
    const int  jr    = wcol + 1;
    int byte = row4 * 16640 + jr * 128 + cc * 16;
    byte ^= (jr & 7) << 4;
    if (valid) {
      const float* src = x + (((size_t)b * C_IN + cc * 8) * H_N + inr) * W_N + wcol;
      float xv[8];
#pragma unroll
      for (int j = 0; j < 8; ++j)
        xv[j] = src[(size_t)j * H_N * W_N];
      float pp = 0.f;
#pragma unroll
      for (int j = 0; j < 8; ++j) pp = fmaf(xv[j], xv[j], pp);
      if      (row4 == 0) part0 += pp;
      else if (row4 == 1) part1 += pp;
      else if (row4 == 2) part2 += pp;
      else                part3 += pp;
      union { __hip_bfloat162 h2[4]; short8v v; } pk;
#pragma unroll
      for (int j = 0; j < 4; ++j)
        pk.h2[j] = __float22bfloat162_rn(make_float2(xv[2 * j], xv[2 * j + 1]));
      *reinterpret_cast<short8v*>(xT + byte) = pk.v;
    } else {
      *reinterpret_cast<short8v*>(xT + byte) = short8v{0,0,0,0,0,0,0,0};
    }
  }
  psacc[cbase][0][wcol] = part0;
  psacc[cbase][1][wcol] = part1;
  psacc[cbase][2][wcol] = part2;
  psacc[cbase][3][wcol] = part3;

  // bias preload (independent; overlaps barrier)
  const float bv0 = bias[wn * 32 + lr];
  const float bv1 = bias[wn * 32 + 16 + lr];

  __syncthreads();                           // xT + psacc ready

  // ---- MFMA: 6 K-steps of 32; B-frags prefetched at top of each step ------
  float4v acc[2][4][2];
#pragma unroll
  for (int o = 0; o < 2; ++o)
#pragma unroll
    for (int ml = 0; ml < 4; ++ml)
#pragma unroll
      for (int nl = 0; nl < 2; ++nl) acc[o][ml][nl] = float4v{0.f, 0.f, 0.f, 0.f};

  const int jbase = wm * 64 + lr;
#pragma unroll
  for (int s = 0; s < 6; ++s) {
    const int kw    = s >> 1;
    const int half  = s & 1;
    const int cslot = half * 4 + lg;
    const int jlow  = (lr + kw) & 7;
    const int base_s = (jbase + kw) * 128 + ((cslot * 16) ^ (jlow << 4));

    // prefetch ALL B-frags of this K-step first (6x global b128, L2-resident)
    short8v bfr[3][2];
#pragma unroll
    for (int r = 0; r < 3; ++r) {
      const int fi = (r * 6 + s) * 8 + wn * 2;
      bfr[r][0] = *reinterpret_cast<const short8v*>(wf + (size_t)(fi + 0) * 512 + l * 8);
      bfr[r][1] = *reinterpret_cast<const short8v*>(wf + (size_t)(fi + 1) * 512 + l * 8);
    }
#pragma unroll
    for (int r = 0; r < 4; ++r) {
      short8v a[4];
#pragma unroll
      for (int ml = 0; ml < 4; ++ml)
        a[ml] = *reinterpret_cast<const short8v*>(xT + base_s + r * 16640 + ml * 2048);
      if (r < 3) {   // o=0, kh=r
#pragma unroll
        for (int ml = 0; ml < 4; ++ml)
#pragma unroll
          for (int nl = 0; nl < 2; ++nl)
            acc[0][ml][nl] = __builtin_amdgcn_mfma_f32_16x16x32_bf16(
                a[ml], bfr[r][nl], acc[0][ml][nl], 0, 0, 0);
      }
      if (r >= 1) {  // o=1, kh=r-1
#pragma unroll
        for (int ml = 0; ml < 4; ++ml)
#pragma unroll
          for (int nl = 0; nl < 2; ++nl)
            acc[1][ml][nl] = __builtin_amdgcn_mfma_f32_16x16x32_bf16(
                a[ml], bfr[r - 1][nl], acc[1][ml][nl], 0, 0, 0);
      }
    }
  }

  // ---- deferred scalar prep (uniform; L2-cached) ---------------------------
  float ssum = 0.f;
#pragma unroll
  for (int i = 0; i < 36; ++i) ssum += partial[i];
  const float nk = sqrtf(ssum);
  const float qe = __builtin_amdgcn_exp2f(q[0] * 1.4426950408889634f);
  const float pe = __builtin_amdgcn_exp2f(p[0] * 1.4426950408889634f);
  const float nlg_nkq = -__builtin_amdgcn_logf(nk + qe);   // -log2(nk+qe)

  // ---- per-pixel pl = pe*(-log2(sqrt(P)+qe) - log2(nk+qe)), direct ---------
  if (t < 256) {
    const int o = t >> 7;        // 0..1
    const int w = t & 127;
    float P = 0.f;
#pragma unroll
    for (int dw = 0; dw < 3; ++dw) {
      const int ww = w + dw - 1;
      if ((unsigned)ww < 128u) {
#pragma unroll
        for (int rr = 0; rr < 3; ++rr)
#pragma unroll
          for (int cc = 0; cc < 4; ++cc)
            P += psacc[cc][o + rr][ww];
      }
    }
    pl[o][w] = pe * (nlg_nkq - __builtin_amdgcn_logf(sqrtf(P) + qe));
  }
  __syncthreads();

  // ---- epilogue: out = copysign(exp2(fma(pe, log2|s|, pl)), s) + bias -----
#pragma unroll
  for (int o = 0; o < 2; ++o) {
    const int oh = h0 + o;
#pragma unroll
    for (int ml = 0; ml < 4; ++ml) {
      const int w0 = wm * 64 + ml * 16 + lg * 4;
      const float4v plv = *reinterpret_cast<const float4v*>(&pl[o][w0]);
#pragma unroll
      for (int nl = 0; nl < 2; ++nl) {
        const int n  = wn * 32 + nl * 16 + lr;
        const float bv = nl ? bv1 : bv0;
        float4v ov;
#pragma unroll
        for (int r = 0; r < 4; ++r) {
          const float sv  = acc[o][ml][nl][r];
          const float lg2 = __builtin_amdgcn_logf(fabsf(sv));   // abs folds into v_log
          const float e   = __builtin_amdgcn_exp2f(fmaf(pe, lg2, plv[r]));
          ov[r] = copysignf(e, sv) + bv;
        }
        *reinterpret_cast<float4v*>(
            out + (((size_t)b * C_OUT + n) * H_N + oh) * W_N + w0) = ov;
      }
    }
  }
}

// ---------------------------------------------------------------------------
extern "C" void kernel_launch(void* const* d_in, const int* in_sizes, int n_in,
                              void* d_out, int out_size, void* d_ws, size_t ws_size,
                              hipStream_t stream) {
  const float* x = (const float*)d_in[0];
  const float* w = (const float*)d_in[1];
  const float* b = (const float*)d_in[2];
  const float* q = (const float*)d_in[3];
  const float* p = (const float*)d_in[4];
  float* out = (float*)d_out;
  float* partial = (float*)d_ws;                               // 36 floats
  unsigned short* wf = (unsigned short*)((char*)d_ws + 256);   // 144KB B-frags

  scs_prep_w<<<36, 256, 0, stream>>>(w, wf, partial);
  scs_main<<<B_N * (H_N / 2), 512, 0, stream>>>(x, wf, b, q, p, partial, out);
}